// Round 7
// baseline (18.322 us; speedup 1.0000x reference)
//
#include <hip/hip_runtime.h>
#include <math.h>

// HybridSymmetricLoss: B=8192, P=4, M=12, 24 perms.
// pairS[p][q] = sum_{i,j} (y[p] ? log a[q] : log1p(-a[q]))  (negated BCE)
// best perm = argmax_sigma sum_p pairS[p][sigma(p)]; category BCE via sigma.
// Single kernel, 1 batch per 64-lane wave, 4 waves/block, 2048 blocks.
// Finish: fence-free packed-atomic tree. Each block does ONE atomicAdd of
// (fixedpoint_value | 1<<42) into 1 of 32 line-padded slots; the 64th
// arrival (detected from the RETURN value -- no separate ticket, no fence)
// forwards (group_total | 1<<58) to a final slot; the 32nd group finisher
// computes the scalar from its return value. Integer adds commute ->
// deterministic. Slots zeroed by an in-graph 4224-B memset.

#define LOG2_CLIP (-144.26950408889634f)   // -100 / ln(2)
#define LN2F      (0.6931471805599453f)
#define FIXSCALE  (16777216.0)             // 2^24

// perm table, lexicographic. byte p = 16*p + 4*sigma(p) = gather lane;
// sigma(p) = (byte_p >> 2) & 3.
#define PK(a,b,c,d) ((unsigned)((4u*(a)) | ((16u+4u*(b))<<8) | \
                                ((32u+4u*(c))<<16) | ((48u+4u*(d))<<24)))
__device__ const unsigned PERM_PK[32] = {
    PK(0,1,2,3), PK(0,1,3,2), PK(0,2,1,3), PK(0,2,3,1), PK(0,3,1,2), PK(0,3,2,1),
    PK(1,0,2,3), PK(1,0,3,2), PK(1,2,0,3), PK(1,2,3,0), PK(1,3,0,2), PK(1,3,2,0),
    PK(2,0,1,3), PK(2,0,3,1), PK(2,1,0,3), PK(2,1,3,0), PK(2,3,0,1), PK(2,3,1,0),
    PK(3,0,1,2), PK(3,0,2,1), PK(3,1,0,2), PK(3,1,2,0), PK(3,2,0,1), PK(3,2,1,0),
    PK(0,1,2,3), PK(0,1,2,3), PK(0,1,2,3), PK(0,1,2,3),
    PK(0,1,2,3), PK(0,1,2,3), PK(0,1,2,3), PK(0,1,2,3)
};

__global__ __launch_bounds__(256) void hsl_fused(
    const float* __restrict__ assign,    // [B,4,12,12]
    const float* __restrict__ cat,       // [B,4]
    const float* __restrict__ alabels,   // [B,4,12,12]
    const float* __restrict__ clabels,   // [B,4]
    unsigned long long* __restrict__ slots,   // [32] stride 16 ull (128B lines)
    unsigned long long* __restrict__ fin,     // [1] final packed accumulator
    float* __restrict__ out,
    int B)
{
    __shared__ float lred[4];

    const int tid  = (int)threadIdx.x;
    const int wib  = tid >> 6;               // wave in block, 0..3
    const int lane = tid & 63;
    const int b    = (int)blockIdx.x * 4 + wib;

    const float* __restrict__ A = assign  + (size_t)b * 576;
    const float* __restrict__ Y = alabels + (size_t)b * 576;

    // s[4p+q] += y[p]*(la[q]-lb[q]);  T[q] += lb[q]   (log2 domain)
    float s[16], T[4];
#pragma unroll
    for (int i = 0; i < 16; ++i) s[i] = 0.0f;
#pragma unroll
    for (int i = 0; i < 4; ++i) T[i] = 0.0f;

#pragma unroll
    for (int it = 0; it < 3; ++it) {
        if (it < 2 || lane < 16) {           // e = lane + 64*it < 144
            const int e = lane + it * 64;
            float d[4], y[4];
#pragma unroll
            for (int q = 0; q < 4; ++q) {
                const float a  = A[q * 144 + e];
                const float la = fmaxf(__log2f(a),        LOG2_CLIP);
                const float lb = fmaxf(__log2f(1.0f - a), LOG2_CLIP);
                d[q] = la - lb;
                T[q] += lb;
            }
#pragma unroll
            for (int p = 0; p < 4; ++p) y[p] = Y[p * 144 + e];
#pragma unroll
            for (int p = 0; p < 4; ++p)
#pragma unroll
                for (int q = 0; q < 4; ++q)
                    s[p * 4 + q] = fmaf(y[p], d[q], s[p * 4 + q]);
        }
    }
#pragma unroll
    for (int i = 0; i < 16; ++i) s[i] += T[i & 3];

    // reduce-scatter butterfly: after 4 split stages lane l holds partial of
    // s[l>>2]; 2 more stages complete the 64-lane sum.
    const bool h32 = (lane & 32) != 0;
    const bool h16 = (lane & 16) != 0;
    const bool h8  = (lane & 8)  != 0;
    const bool h4  = (lane & 4)  != 0;

    float t[8];
#pragma unroll
    for (int i = 0; i < 8; ++i) {
        const float keep = h32 ? s[i + 8] : s[i];
        const float send = h32 ? s[i]     : s[i + 8];
        t[i] = keep + __shfl_xor(send, 32, 64);
    }
    float u[4];
#pragma unroll
    for (int i = 0; i < 4; ++i) {
        const float keep = h16 ? t[i + 4] : t[i];
        const float send = h16 ? t[i]     : t[i + 4];
        u[i] = keep + __shfl_xor(send, 16, 64);
    }
    float w[2];
#pragma unroll
    for (int i = 0; i < 2; ++i) {
        const float keep = h8 ? u[i + 2] : u[i];
        const float send = h8 ? u[i]     : u[i + 2];
        w[i] = keep + __shfl_xor(send, 8, 64);
    }
    float x;
    {
        const float keep = h4 ? w[1] : w[0];
        const float send = h4 ? w[0] : w[1];
        x = keep + __shfl_xor(send, 4, 64);
    }
    x += __shfl_xor(x, 2, 64);
    x += __shfl_xor(x, 1, 64);
    // lane l: x == total s[l >> 2]

    // perm-parallel scoring: lane j < 24 evaluates perm j
    unsigned pk = PERM_PK[lane & 31];
    const float v0 = __shfl(x, (int)( pk        & 0xFFu), 64);
    const float v1 = __shfl(x, (int)((pk >> 8)  & 0xFFu), 64);
    const float v2 = __shfl(x, (int)((pk >> 16) & 0xFFu), 64);
    const float v3 = __shfl(x, (int)( pk >> 24        ), 64);
    float score = (v0 + v1) + (v2 + v3);
    if (lane >= 24) score = -__builtin_huge_valf();

    // max-butterfly over lanes 0..31 (covers all 24 perms), carry pk
#pragma unroll
    for (int m = 16; m >= 1; m >>= 1) {
        const float    os  = __shfl_xor(score, m, 64);
        const unsigned opk = __shfl_xor(pk,    m, 64);
        const bool take = os > score;
        score = take ? os  : score;
        pk    = take ? opk : pk;
    }

    if (lane == 0) {
        const float* __restrict__ C  = cat     + (size_t)b * 4;
        const float* __restrict__ CY = clabels + (size_t)b * 4;
        float cs2 = 0.0f;
#pragma unroll
        for (int p = 0; p < 4; ++p) {
            const int q  = (int)((pk >> (8 * p + 2)) & 3u);
            const float c  = C[q];
            const float yv = CY[p];
            const float l2 = (yv != 0.0f) ? fmaxf(__log2f(c), LOG2_CLIP)
                                          : fmaxf(__log2f(1.0f - c), LOG2_CLIP);
            cs2 += l2;
        }
        // per-batch contribution (>= 0): -ln2 * (score/576 + cs2/8)
        lred[wib] = -LN2F * (score * (1.0f / 576.0f) + 0.125f * cs2);
    }
    __syncthreads();

    if (tid == 0) {
        const float v = (lred[0] + lred[1]) + (lred[2] + lred[3]);
        // pack: value in bits 0..41 (2^24 fixed-point; block value < 600
        // -> < 2^34; 64-block group sum < 2^40), arrival count at bit 42.
        const unsigned long long me =
            (unsigned long long)((double)v * FIXSCALE + 0.5) | (1ULL << 42);
        const int g = (int)(blockIdx.x & 31);
        const unsigned long long old = atomicAdd(&slots[g * 16], me);
        if ((old >> 42) == 63ULL) {
            // 64th arrival in this group: old+me holds the full group word.
            const unsigned long long gtot =
                (old + me) & ((1ULL << 42) - 1ULL);
            // level 2: value bits 0..57 (sum of 32 group totals < 2^47),
            // count at bit 58 (32 -> bit 63, no overflow).
            const unsigned long long me2 = gtot | (1ULL << 58);
            const unsigned long long old2 = atomicAdd(fin, me2);
            if ((old2 >> 58) == 31ULL) {
                const unsigned long long tot =
                    (old2 + me2) & ((1ULL << 58) - 1ULL);
                out[0] = (float)((double)tot / FIXSCALE / (double)B);
            }
        }
    }
}

extern "C" void kernel_launch(void* const* d_in, const int* in_sizes, int n_in,
                              void* d_out, int out_size, void* d_ws, size_t ws_size,
                              hipStream_t stream) {
    const float* assign  = (const float*)d_in[0];
    const float* cat     = (const float*)d_in[1];
    const float* alabels = (const float*)d_in[2];
    const float* clabels = (const float*)d_in[3];
    float* out = (float*)d_out;

    const int B = in_sizes[0] / 576;  // 8192
    unsigned long long* slots = (unsigned long long*)d_ws;       // 32 x 128B
    unsigned long long* fin   = slots + 32 * 16;                 // 1 line

    hipMemsetAsync(d_ws, 0, 33 * 128, stream);

    const int nblocks = B / 4;        // 2048: 32 groups of 64
    hipLaunchKernelGGL(hsl_fused, dim3(nblocks), dim3(256), 0, stream,
                       assign, cat, alabels, clabels, slots, fin, out, B);
}

// Round 8
// 14.420 us; speedup vs baseline: 1.2706x; 1.2706x over previous
//
#include <hip/hip_runtime.h>
#include <math.h>

// HybridSymmetricLoss: B=8192, P=4, M=12, 24 perms.
// pairS[p][q] = sum_{i,j} (y[p] ? log a[q] : log1p(-a[q]))  (negated BCE)
// best perm = argmax_sigma sum_p pairS[p][sigma(p)]; category BCE via sigma.
// kernel1 (round-5 exact, measured best): 1 batch per 64-lane wave, 4 waves
//   per 256-thread block, 2048 blocks (8 blocks/CU, 32 waves/CU); per-block
//   partial plain-stored (no atomics, no fences -- r4/r7 showed same-line
//   RMW + extra graph nodes regress).
// kernel2: barrier-minimal single-block reduce: float4 loads, per-wave
//   double butterfly (no barriers), 4 LDS values, 1 barrier, lane-0 combine.

#define LOG2_CLIP (-144.26950408889634f)   // -100 / ln(2)
#define LN2F      (0.6931471805599453f)

// perm table, lexicographic. byte p = 16*p + 4*sigma(p) = gather lane;
// sigma(p) = (byte_p >> 2) & 3.
#define PK(a,b,c,d) ((unsigned)((4u*(a)) | ((16u+4u*(b))<<8) | \
                                ((32u+4u*(c))<<16) | ((48u+4u*(d))<<24)))
__device__ const unsigned PERM_PK[32] = {
    PK(0,1,2,3), PK(0,1,3,2), PK(0,2,1,3), PK(0,2,3,1), PK(0,3,1,2), PK(0,3,2,1),
    PK(1,0,2,3), PK(1,0,3,2), PK(1,2,0,3), PK(1,2,3,0), PK(1,3,0,2), PK(1,3,2,0),
    PK(2,0,1,3), PK(2,0,3,1), PK(2,1,0,3), PK(2,1,3,0), PK(2,3,0,1), PK(2,3,1,0),
    PK(3,0,1,2), PK(3,0,2,1), PK(3,1,0,2), PK(3,1,2,0), PK(3,2,0,1), PK(3,2,1,0),
    PK(0,1,2,3), PK(0,1,2,3), PK(0,1,2,3), PK(0,1,2,3),
    PK(0,1,2,3), PK(0,1,2,3), PK(0,1,2,3), PK(0,1,2,3)
};

__global__ __launch_bounds__(256) void hsl_partial(
    const float* __restrict__ assign,    // [B,4,12,12]
    const float* __restrict__ cat,       // [B,4]
    const float* __restrict__ alabels,   // [B,4,12,12]
    const float* __restrict__ clabels,   // [B,4]
    float* __restrict__ bsums)           // [nblocks] per-block partial
{
    __shared__ float lred[4];

    const int tid  = (int)threadIdx.x;
    const int wib  = tid >> 6;               // wave in block, 0..3
    const int lane = tid & 63;
    const int b    = (int)blockIdx.x * 4 + wib;

    const float* __restrict__ A = assign  + (size_t)b * 576;
    const float* __restrict__ Y = alabels + (size_t)b * 576;

    // s[4p+q] += y[p]*(la[q]-lb[q]);  T[q] += lb[q]   (log2 domain)
    float s[16], T[4];
#pragma unroll
    for (int i = 0; i < 16; ++i) s[i] = 0.0f;
#pragma unroll
    for (int i = 0; i < 4; ++i) T[i] = 0.0f;

#pragma unroll
    for (int it = 0; it < 3; ++it) {
        if (it < 2 || lane < 16) {           // e = lane + 64*it < 144
            const int e = lane + it * 64;
            float d[4], y[4];
#pragma unroll
            for (int q = 0; q < 4; ++q) {
                const float a  = A[q * 144 + e];
                const float la = fmaxf(__log2f(a),        LOG2_CLIP);
                const float lb = fmaxf(__log2f(1.0f - a), LOG2_CLIP);
                d[q] = la - lb;
                T[q] += lb;
            }
#pragma unroll
            for (int p = 0; p < 4; ++p) y[p] = Y[p * 144 + e];
#pragma unroll
            for (int p = 0; p < 4; ++p)
#pragma unroll
                for (int q = 0; q < 4; ++q)
                    s[p * 4 + q] = fmaf(y[p], d[q], s[p * 4 + q]);
        }
    }
#pragma unroll
    for (int i = 0; i < 16; ++i) s[i] += T[i & 3];

    // reduce-scatter butterfly: after 4 split stages lane l holds partial of
    // s[l>>2]; 2 more stages complete the 64-lane sum.
    const bool h32 = (lane & 32) != 0;
    const bool h16 = (lane & 16) != 0;
    const bool h8  = (lane & 8)  != 0;
    const bool h4  = (lane & 4)  != 0;

    float t[8];
#pragma unroll
    for (int i = 0; i < 8; ++i) {
        const float keep = h32 ? s[i + 8] : s[i];
        const float send = h32 ? s[i]     : s[i + 8];
        t[i] = keep + __shfl_xor(send, 32, 64);
    }
    float u[4];
#pragma unroll
    for (int i = 0; i < 4; ++i) {
        const float keep = h16 ? t[i + 4] : t[i];
        const float send = h16 ? t[i]     : t[i + 4];
        u[i] = keep + __shfl_xor(send, 16, 64);
    }
    float w[2];
#pragma unroll
    for (int i = 0; i < 2; ++i) {
        const float keep = h8 ? u[i + 2] : u[i];
        const float send = h8 ? u[i]     : u[i + 2];
        w[i] = keep + __shfl_xor(send, 8, 64);
    }
    float x;
    {
        const float keep = h4 ? w[1] : w[0];
        const float send = h4 ? w[0] : w[1];
        x = keep + __shfl_xor(send, 4, 64);
    }
    x += __shfl_xor(x, 2, 64);
    x += __shfl_xor(x, 1, 64);
    // lane l: x == total s[l >> 2]

    // perm-parallel scoring: lane j < 24 evaluates perm j
    unsigned pk = PERM_PK[lane & 31];
    const float v0 = __shfl(x, (int)( pk        & 0xFFu), 64);
    const float v1 = __shfl(x, (int)((pk >> 8)  & 0xFFu), 64);
    const float v2 = __shfl(x, (int)((pk >> 16) & 0xFFu), 64);
    const float v3 = __shfl(x, (int)( pk >> 24        ), 64);
    float score = (v0 + v1) + (v2 + v3);
    if (lane >= 24) score = -__builtin_huge_valf();

    // max-butterfly over lanes 0..31 (covers all 24 perms), carry pk
#pragma unroll
    for (int m = 16; m >= 1; m >>= 1) {
        const float    os  = __shfl_xor(score, m, 64);
        const unsigned opk = __shfl_xor(pk,    m, 64);
        const bool take = os > score;
        score = take ? os  : score;
        pk    = take ? opk : pk;
    }

    if (lane == 0) {
        const float* __restrict__ C  = cat     + (size_t)b * 4;
        const float* __restrict__ CY = clabels + (size_t)b * 4;
        float cs2 = 0.0f;
#pragma unroll
        for (int p = 0; p < 4; ++p) {
            const int q  = (int)((pk >> (8 * p + 2)) & 3u);
            const float c  = C[q];
            const float yv = CY[p];
            const float l2 = (yv != 0.0f) ? fmaxf(__log2f(c), LOG2_CLIP)
                                          : fmaxf(__log2f(1.0f - c), LOG2_CLIP);
            cs2 += l2;
        }
        // per-batch contribution (>= 0): -ln2 * (score/576 + cs2/8)
        lred[wib] = -LN2F * (score * (1.0f / 576.0f) + 0.125f * cs2);
    }
    __syncthreads();

    if (tid == 0) {
        bsums[blockIdx.x] = (lred[0] + lred[1]) + (lred[2] + lred[3]);
    }
}

__global__ __launch_bounds__(256) void hsl_reduce(
    const float* __restrict__ bsums,     // [n] per-block partials
    float* __restrict__ out,
    int n, int B)
{
    __shared__ double sw[4];
    const int tid  = (int)threadIdx.x;
    const int wid  = tid >> 6;
    const int lane = tid & 63;

    // n = 2048 -> 512 float4; 256 threads -> 2 each, fixed assignment
    const float4* __restrict__ v4 = (const float4*)bsums;
    const int n4 = n >> 2;
    double d = 0.0;
    for (int i = tid; i < n4; i += 256) {
        const float4 v = v4[i];
        d += (double)((v.x + v.y) + (v.z + v.w));
    }

    // per-wave butterfly, no barriers, fixed order
#pragma unroll
    for (int m = 32; m >= 1; m >>= 1)
        d += __shfl_xor(d, m, 64);

    if (lane == 0) sw[wid] = d;
    __syncthreads();

    if (tid == 0) {
        const double t = (sw[0] + sw[1]) + (sw[2] + sw[3]);
        out[0] = (float)(t / (double)B);
    }
}

extern "C" void kernel_launch(void* const* d_in, const int* in_sizes, int n_in,
                              void* d_out, int out_size, void* d_ws, size_t ws_size,
                              hipStream_t stream) {
    const float* assign  = (const float*)d_in[0];
    const float* cat     = (const float*)d_in[1];
    const float* alabels = (const float*)d_in[2];
    const float* clabels = (const float*)d_in[3];
    float* out = (float*)d_out;

    const int B = in_sizes[0] / 576;  // 8192
    float* bsums = (float*)d_ws;

    const int nblocks = B / 4;        // 4 batches per 256-thread block
    hipLaunchKernelGGL(hsl_partial, dim3(nblocks), dim3(256), 0, stream,
                       assign, cat, alabels, clabels, bsums);
    hipLaunchKernelGGL(hsl_reduce, dim3(1), dim3(256), 0, stream,
                       bsums, out, nblocks, B);
}